// Round 12
// baseline (821.259 us; speedup 1.0000x reference)
//
#include <hip/hip_runtime.h>
#include <hip/hip_bf16.h>
#include <stdint.h>

#define DEV_INLINE __device__ __forceinline__

typedef __attribute__((ext_vector_type(4))) float f32x4;
typedef __attribute__((ext_vector_type(8))) __bf16 bf16x8;
typedef __attribute__((ext_vector_type(8))) unsigned short u16x8;

// problem dims
constexpr int Hh = 32, KVc = 8, Dd = 128, Gg = 4, Nn = 16;

DEV_INLINE unsigned short f32_to_bf16(float f) {
  unsigned u = __float_as_uint(f);
  u += 0x7fffu + ((u >> 16) & 1u);   // round-to-nearest-even
  return (unsigned short)(u >> 16);
}
DEV_INLINE float bf16_lo(unsigned u) { return __uint_as_float(u << 16); }
DEV_INLINE float bf16_hi(unsigned u) { return __uint_as_float(u & 0xffff0000u); }

// ---------------- merged cast f32 -> bf16 (6 segments, 1 launch) ----------
// Every segment runs EXACTLY 16 iterations/thread (n8 == 16 * nb * 256), so
// the 4-wide unroll below has no remainder. 8 independent f32x4 loads are
// issued per unrolled step (128 B/thread in flight) before the dependent
// cvt+store groups — MLP was the r10-measured gate, not width.
__global__ __launch_bounds__(256) void cast_all_kernel(
    const float* __restrict__ s0, unsigned short* __restrict__ d0,   // hs
    const float* __restrict__ s1, unsigned short* __restrict__ d1,   // Wq
    const float* __restrict__ s2, unsigned short* __restrict__ d2,   // rhs
    const float* __restrict__ s3, unsigned short* __restrict__ d3,   // Wk
    const float* __restrict__ s4, unsigned short* __restrict__ d4,   // Wv
    const float* __restrict__ s5, unsigned short* __restrict__ d5,   // Wo
    float qscale) {
  const int b = blockIdx.x;
  const float* src; unsigned short* dst; int n8, b0, nb; float sc = 1.f;
  if (b < 512)       { src = s0; dst = d0; n8 = 2097152; b0 = 0;    nb = 512; }
  else if (b < 1024) { src = s1; dst = d1; n8 = 2097152; b0 = 512;  nb = 512; sc = qscale; }
  else if (b < 3072) { src = s2; dst = d2; n8 = 8388608; b0 = 1024; nb = 2048; }
  else if (b < 3104) { src = s3; dst = d3; n8 = 131072;  b0 = 3072; nb = 32; }
  else if (b < 3136) { src = s4; dst = d4; n8 = 131072;  b0 = 3104; nb = 32; }
  else               { src = s5; dst = d5; n8 = 2097152; b0 = 3136; nb = 512; }
  const f32x4* sp = reinterpret_cast<const f32x4*>(src);
  u16x8* dp = reinterpret_cast<u16x8*>(dst);
  const int s = nb * 256;                       // per-iteration stride
  for (int i = (b - b0) * 256 + threadIdx.x; i < n8; i += 4 * s) {
    // issue all 8 loads first (independent)
    f32x4 a0 = sp[2 * i];            f32x4 a1 = sp[2 * i + 1];
    f32x4 b0v = sp[2 * (i + s)];     f32x4 b1v = sp[2 * (i + s) + 1];
    f32x4 c0 = sp[2 * (i + 2 * s)];  f32x4 c1 = sp[2 * (i + 2 * s) + 1];
    f32x4 e0 = sp[2 * (i + 3 * s)];  f32x4 e1 = sp[2 * (i + 3 * s) + 1];
    u16x8 o;
    o[0] = f32_to_bf16(a0.x * sc); o[1] = f32_to_bf16(a0.y * sc);
    o[2] = f32_to_bf16(a0.z * sc); o[3] = f32_to_bf16(a0.w * sc);
    o[4] = f32_to_bf16(a1.x * sc); o[5] = f32_to_bf16(a1.y * sc);
    o[6] = f32_to_bf16(a1.z * sc); o[7] = f32_to_bf16(a1.w * sc);
    dp[i] = o;
    o[0] = f32_to_bf16(b0v.x * sc); o[1] = f32_to_bf16(b0v.y * sc);
    o[2] = f32_to_bf16(b0v.z * sc); o[3] = f32_to_bf16(b0v.w * sc);
    o[4] = f32_to_bf16(b1v.x * sc); o[5] = f32_to_bf16(b1v.y * sc);
    o[6] = f32_to_bf16(b1v.z * sc); o[7] = f32_to_bf16(b1v.w * sc);
    dp[i + s] = o;
    o[0] = f32_to_bf16(c0.x * sc); o[1] = f32_to_bf16(c0.y * sc);
    o[2] = f32_to_bf16(c0.z * sc); o[3] = f32_to_bf16(c0.w * sc);
    o[4] = f32_to_bf16(c1.x * sc); o[5] = f32_to_bf16(c1.y * sc);
    o[6] = f32_to_bf16(c1.z * sc); o[7] = f32_to_bf16(c1.w * sc);
    dp[i + 2 * s] = o;
    o[0] = f32_to_bf16(e0.x * sc); o[1] = f32_to_bf16(e0.y * sc);
    o[2] = f32_to_bf16(e0.z * sc); o[3] = f32_to_bf16(e0.w * sc);
    o[4] = f32_to_bf16(e1.x * sc); o[5] = f32_to_bf16(e1.y * sc);
    o[6] = f32_to_bf16(e1.z * sc); o[7] = f32_to_bf16(e1.w * sc);
    dp[i + 3 * s] = o;
  }
}

// ---------------- GEMM body: C[M][N] = A[M][K] * B[N][K]^T ----------------
// r3 best-measured structure: 256x256 tile, BK=32, 512 threads (8 waves
// 2m x 4n), ring-4 LDS, 2-tile unrolled K-loop with register fragment
// double-buffering, counted lgkm/vm waits, setprio, XOR bank swizzle
// (0 conflicts measured), XCD-aware block swizzle. LDS passed in by the
// kernel so multiple call-sites share one allocation.
template <bool OUT_BF16>
DEV_INLINE void gemm256_body(const unsigned short* __restrict__ A,
                             const unsigned short* __restrict__ Bw,
                             void* __restrict__ Cout, int M, int N, int K,
                             int bid, int nwg,
                             unsigned short* AlsB, unsigned short* BlsB) {
  const int tid = threadIdx.x;
  const int wave = tid >> 6, lane = tid & 63;
  const int wm = wave >> 2, wn = wave & 3;       // 2 x 4 wave grid
  const int lrow = lane & 15, lhi = lane >> 4;
  const int swslot = (lhi ^ ((lrow >> 1) & 3)) << 4;

  // XCD-aware block swizzle (T1); nwg % 8 == 0 for all our grids
  const int ntn = N >> 8;
  const int swz = ((nwg & 7) == 0) ? ((bid & 7) * (nwg >> 3) + (bid >> 3)) : bid;
  const int tm = swz / ntn, tn = swz - tm * ntn;

  const unsigned short* Abase = A + (long)tm * 256 * K;
  const unsigned short* Bbase = Bw + (long)tn * 256 * K;
  const int ktiles = K >> 5;   // always even here (128 or 32)

  auto slotA = [&](int s) { return AlsB + s * 8192; };
  auto slotB = [&](int s) { return BlsB + s * 8192; };

  // stage one 256x32 bf16 tile; linear LDS dest, inverse-swizzled global src
  auto stage = [&](const unsigned short* gbase, unsigned short* lslot, int k0) {
#pragma unroll
    for (int j = 0; j < 2; ++j) {
      int c = (j << 9) + tid;              // chunk 0..1023 (16B each)
      int row = c >> 2;
      int gslot = (c & 3) ^ ((row >> 1) & 3);
      const unsigned short* g = gbase + (long)row * K + k0 + (gslot << 3);
      int ldsoff = (((j << 9) + (wave << 6)) << 4);  // wave-uniform base
      __builtin_amdgcn_global_load_lds(
          (const __attribute__((address_space(1))) unsigned int*)g,
          (__attribute__((address_space(3))) unsigned int*)((char*)lslot + ldsoff),
          16, 0, 0);
    }
  };

#define RD_B(dst, Bc)                                                      \
  _Pragma("unroll") for (int n = 0; n < 4; ++n) dst[n] =                   \
      *reinterpret_cast<const bf16x8*>(                                    \
          (Bc) + (((wn << 6) + (n << 4) + lrow) << 6) + swslot);
#define RD_A(dst, Ac, mh)                                                  \
  _Pragma("unroll") for (int m = 0; m < 4; ++m) dst[m] =                   \
      *reinterpret_cast<const bf16x8*>(                                    \
          (Ac) + (((wm << 7) + ((mh) << 6) + (m << 4) + lrow) << 6) + swslot);
#define MFMA16(accrow, af, bf)                                             \
  _Pragma("unroll") for (int m = 0; m < 4; ++m)                            \
  _Pragma("unroll") for (int n = 0; n < 4; ++n)                            \
      acc[(accrow) + m][n] = __builtin_amdgcn_mfma_f32_16x16x32_bf16(      \
          af[m], bf[n], acc[(accrow) + m][n], 0, 0, 0);

  f32x4 acc[8][4];
#pragma unroll
  for (int m = 0; m < 8; ++m)
#pragma unroll
    for (int n = 0; n < 4; ++n) acc[m][n] = {0.f, 0.f, 0.f, 0.f};

  // prologue: stage tiles 0..2, wait tile 0 landed, prefetch slot-0 frags
#pragma unroll
  for (int p = 0; p < 3; ++p) {
    if (p < ktiles) {
      stage(Abase, slotA(p), p << 5);
      stage(Bbase, slotB(p), p << 5);
    }
  }
  if (ktiles > 2) asm volatile("s_waitcnt vmcnt(8)" ::: "memory");
  else            asm volatile("s_waitcnt vmcnt(0)" ::: "memory");
  __builtin_amdgcn_s_barrier();

  bf16x8 bfrE[4], afrE[4], bfrO[4], afrO[4], afrH[4];
  RD_B(bfrE, (const char*)slotB(0));
  RD_A(afrE, (const char*)slotA(0), 0);

  for (int t0 = 0; t0 < ktiles; t0 += 2) {
    const int t1 = t0 + 1;
    const char* Ac1 = (const char*)slotA(t1 & 3);
    const char* Bc1 = (const char*)slotB(t1 & 3);
    const char* Ac0 = (const char*)slotA(t0 & 3);
    const int sp = (t0 + 3) & 3;   // ring slot for tiles t0+3 / t1+3

    // ---- P0: MFMA tile t0 m0-3; prefetch A m4-7(t0); stage A(t0+3) ----
    RD_A(afrH, Ac0, 1);
    if (t0 + 3 < ktiles) stage(Abase, slotA(sp), (t0 + 3) << 5);
    asm volatile("s_waitcnt lgkmcnt(4)" ::: "memory");  // bfrE/afrE ready
    __builtin_amdgcn_s_setprio(1);
    MFMA16(0, afrE, bfrE);
    __builtin_amdgcn_s_setprio(0);
    if (t0 + 3 < ktiles)      asm volatile("s_waitcnt vmcnt(6)" ::: "memory");
    else if (t0 + 2 < ktiles) asm volatile("s_waitcnt vmcnt(4)" ::: "memory");
    else                      asm volatile("s_waitcnt vmcnt(0)" ::: "memory");
    __builtin_amdgcn_s_barrier();   // tile t1 landed for everyone

    // ---- P1: MFMA tile t0 m4-7; prefetch frags(t1); stage B(t0+3) ----
    RD_B(bfrO, Bc1);
    RD_A(afrO, Ac1, 0);
    if (t0 + 3 < ktiles) stage(Bbase, slotB(sp), (t0 + 3) << 5);
    asm volatile("s_waitcnt lgkmcnt(8)" ::: "memory");  // afrH ready
    __builtin_amdgcn_s_setprio(1);
    MFMA16(4, afrH, bfrE);
    __builtin_amdgcn_s_setprio(0);
    __builtin_amdgcn_s_barrier();   // slot (t0-1) reads done -> P2 stage safe

    // ---- P2: MFMA tile t1 m0-3; prefetch A m4-7(t1); stage A(t1+3) ----
    RD_A(afrH, Ac1, 1);
    if (t1 + 3 < ktiles) stage(Abase, slotA(t0 & 3), (t1 + 3) << 5);
    asm volatile("s_waitcnt lgkmcnt(4)" ::: "memory");  // bfrO/afrO ready
    __builtin_amdgcn_s_setprio(1);
    MFMA16(0, afrO, bfrO);
    __builtin_amdgcn_s_setprio(0);
    if (t1 + 3 < ktiles)      asm volatile("s_waitcnt vmcnt(6)" ::: "memory");
    else if (t1 + 2 < ktiles) asm volatile("s_waitcnt vmcnt(4)" ::: "memory");
    else                      asm volatile("s_waitcnt vmcnt(0)" ::: "memory");
    __builtin_amdgcn_s_barrier();   // tile t0+2 landed for everyone

    // ---- P3: MFMA tile t1 m4-7; prefetch frags(t0+2); stage B(t1+3) ----
    if (t0 + 2 < ktiles) {
      const char* Bc2 = (const char*)slotB((t0 + 2) & 3);
      const char* Ac2 = (const char*)slotA((t0 + 2) & 3);
      RD_B(bfrE, Bc2);
      RD_A(afrE, Ac2, 0);
    }
    if (t1 + 3 < ktiles) stage(Bbase, slotB(t0 & 3), (t1 + 3) << 5);
    if (t0 + 2 < ktiles) asm volatile("s_waitcnt lgkmcnt(8)" ::: "memory");
    else                 asm volatile("s_waitcnt lgkmcnt(0)" ::: "memory");
    __builtin_amdgcn_s_setprio(1);
    MFMA16(4, afrH, bfrO);
    __builtin_amdgcn_s_setprio(0);
    __builtin_amdgcn_s_barrier();   // slot t0 reads done -> next P0 stage safe
  }

  // epilogue: C/D layout col = lane&15, row = (lane>>4)*4 + r
#pragma unroll
  for (int m = 0; m < 8; ++m) {
#pragma unroll
    for (int n = 0; n < 4; ++n) {
      long r0 = (long)tm * 256 + (wm << 7) + (m << 4) + (lhi << 2);
      long c0 = (long)tn * 256 + (wn << 6) + (n << 4) + lrow;
#pragma unroll
      for (int r = 0; r < 4; ++r) {
        float v = acc[m][n][r];
        if constexpr (OUT_BF16)
          ((unsigned short*)Cout)[(r0 + r) * N + c0] = f32_to_bf16(v);
        else
          ((float*)Cout)[(r0 + r) * N + c0] = v;
      }
    }
  }
#undef RD_A
#undef RD_B
#undef MFMA16
}

// merged Q/K/V GEMM: blocks [0,256) = Q (long blocks first for LPT packing),
// [256,1280) = K, [1280,2304) = V. One shared LDS allocation.
__global__ __launch_bounds__(512, 2) void gemm_qkv_kernel(
    const unsigned short* __restrict__ hsb, const unsigned short* __restrict__ Wqb,
    unsigned short* __restrict__ Qb,
    const unsigned short* __restrict__ rhsb,
    const unsigned short* __restrict__ Wkb, unsigned short* __restrict__ Kb,
    const unsigned short* __restrict__ Wvb, unsigned short* __restrict__ Vb) {
  __shared__ alignas(16) unsigned short Als[4][8192];
  __shared__ alignas(16) unsigned short Bls[4][8192];
  const int b = blockIdx.x;
  const unsigned short *Ap, *Bp; unsigned short* Cp; int M, N, K, bid, nwg;
  if (b < 256)       { Ap = hsb;  Bp = Wqb; Cp = Qb; M = 4096;  N = 4096; K = 4096; bid = b;        nwg = 256; }
  else if (b < 1280) { Ap = rhsb; Bp = Wkb; Cp = Kb; M = 65536; N = 1024; K = 1024; bid = b - 256;  nwg = 1024; }
  else               { Ap = rhsb; Bp = Wvb; Cp = Vb; M = 65536; N = 1024; K = 1024; bid = b - 1280; nwg = 1024; }
  gemm256_body<true>(Ap, Bp, Cp, M, N, K, bid, nwg, &Als[0][0], &Bls[0][0]);
}

// standalone GEMM (used for the f32-output out-projection)
template <bool OUT_BF16>
__global__ __launch_bounds__(512, 2) void gemm256_kernel(
    const unsigned short* __restrict__ A, const unsigned short* __restrict__ Bw,
    void* __restrict__ Cout, int M, int N, int K) {
  __shared__ alignas(16) unsigned short Als[4][8192];
  __shared__ alignas(16) unsigned short Bls[4][8192];
  gemm256_body<OUT_BF16>(A, Bw, Cout, M, N, K, blockIdx.x, gridDim.x,
                         &Als[0][0], &Bls[0][0]);
}

// ---------------- grouped neighbor attention ----------------
// one wave per (b*s, kv); lane = g*16 + i
__global__ __launch_bounds__(256) void attn_kernel(
    const unsigned short* __restrict__ Q,   // [B*S][H*D] bf16 (pre-scaled)
    const unsigned short* __restrict__ Kf,  // [B*S*N][KV*D] bf16
    const unsigned short* __restrict__ Vf,  // [B*S*N][KV*D] bf16
    unsigned short* __restrict__ O) {       // [B*S][H*D] bf16
  const int tid = threadIdx.x;
  const int wave = tid >> 6;
  const int lane = tid & 63;
  const int sl = blockIdx.x * 4 + wave;  // [0, B*S*KV)
  const int bs = sl >> 3;
  const int kv = sl & 7;
  const int g = lane >> 4;
  const int i = lane & 15;

  const unsigned short* qrow = Q + (long)bs * (Hh * Dd) + (kv * Gg + g) * Dd;
  const int ni = 2 * kv + (i >> 3);
  const unsigned short* krow =
      Kf + ((long)bs * Nn + ni) * (KVc * Dd) + (i & 7) * Dd;

  float s = 0.f;
#pragma unroll
  for (int c = 0; c < 16; ++c) {
    uint4 qu = *reinterpret_cast<const uint4*>(qrow + c * 8);
    uint4 ku = *reinterpret_cast<const uint4*>(krow + c * 8);
    s += bf16_lo(qu.x) * bf16_lo(ku.x) + bf16_hi(qu.x) * bf16_hi(ku.x);
    s += bf16_lo(qu.y) * bf16_lo(ku.y) + bf16_hi(qu.y) * bf16_hi(ku.y);
    s += bf16_lo(qu.z) * bf16_lo(ku.z) + bf16_hi(qu.z) * bf16_hi(ku.z);
    s += bf16_lo(qu.w) * bf16_lo(ku.w) + bf16_hi(qu.w) * bf16_hi(ku.w);
  }

  float mx = s;
#pragma unroll
  for (int off = 8; off >= 1; off >>= 1) mx = fmaxf(mx, __shfl_xor(mx, off));
  float p = __expf(s - mx);
  float sum = p;
#pragma unroll
  for (int off = 8; off >= 1; off >>= 1) sum += __shfl_xor(sum, off);
  p = p / sum;

  float o[8] = {0.f, 0.f, 0.f, 0.f, 0.f, 0.f, 0.f, 0.f};
  const long vbase = (long)bs * Nn * (KVc * Dd);
#pragma unroll
  for (int ii = 0; ii < 16; ++ii) {
    float pi = __shfl(p, (lane & 48) | ii);
    const unsigned short* vrow = Vf + vbase +
        (long)(2 * kv + (ii >> 3)) * (KVc * Dd) + (ii & 7) * Dd + i * 8;
    uint4 vu = *reinterpret_cast<const uint4*>(vrow);
    o[0] += pi * bf16_lo(vu.x); o[1] += pi * bf16_hi(vu.x);
    o[2] += pi * bf16_lo(vu.y); o[3] += pi * bf16_hi(vu.y);
    o[4] += pi * bf16_lo(vu.z); o[5] += pi * bf16_hi(vu.z);
    o[6] += pi * bf16_lo(vu.w); o[7] += pi * bf16_hi(vu.w);
  }
  u16x8 ov;
#pragma unroll
  for (int d = 0; d < 8; ++d) ov[d] = f32_to_bf16(o[d]);
  *reinterpret_cast<u16x8*>(O + (long)bs * (Hh * Dd) + (kv * Gg + g) * Dd +
                            i * 8) = ov;
}

// ---------------- launch ----------------
extern "C" void kernel_launch(void* const* d_in, const int* in_sizes, int n_in,
                              void* d_out, int out_size, void* d_ws,
                              size_t ws_size, hipStream_t stream) {
  (void)in_sizes; (void)n_in; (void)out_size; (void)ws_size;
  const float* hs = (const float*)d_in[0];   // [2,2048,4096]
  const float* rhs = (const float*)d_in[1];  // [2,2048,16,1024]
  const float* Wq = (const float*)d_in[2];   // [4096,4096]
  const float* Wk = (const float*)d_in[3];   // [1024,1024]
  const float* Wv = (const float*)d_in[4];   // [1024,1024]
  const float* Wo = (const float*)d_in[5];   // [4096,4096]
  float* out = (float*)d_out;                // [2,2048,4096] f32

  char* ws = (char*)d_ws;
  size_t off = 0;
  auto alloc = [&](size_t bytes) { char* p = ws + off; off += bytes; return p; };
  unsigned short* hsb  = (unsigned short*)alloc(16777216ull * 2);
  unsigned short* Wqb  = (unsigned short*)alloc(16777216ull * 2);
  unsigned short* rhsb = (unsigned short*)alloc(67108864ull * 2);
  unsigned short* Wkb  = (unsigned short*)alloc(1048576ull * 2);
  unsigned short* Wvb  = (unsigned short*)alloc(1048576ull * 2);
  unsigned short* Wob  = (unsigned short*)alloc(16777216ull * 2);
  unsigned short* Qb   = (unsigned short*)alloc(16777216ull * 2);
  unsigned short* Kb   = (unsigned short*)alloc(67108864ull * 2);
  unsigned short* Vb   = (unsigned short*)alloc(67108864ull * 2);
  unsigned short* Ab   = (unsigned short*)alloc(16777216ull * 2);

  const float scaler = 0.08838834764831845f;  // D^-0.5, folded into Wq

  // all six f32->bf16 casts in one launch (3648 blocks, block-partitioned)
  cast_all_kernel<<<3648, 256, 0, stream>>>(hs, hsb, Wq, Wqb, rhs, rhsb,
                                            Wk, Wkb, Wv, Wvb, Wo, Wob, scaler);

  // Q,K,V gemms merged into one dispatch (LPT packing: 256 long Q-blocks
  // first, then 2x1024 short K/V blocks backfill)
  gemm_qkv_kernel<<<2304, 512, 0, stream>>>(hsb, Wqb, Qb, rhsb, Wkb, Kb,
                                            Wvb, Vb);
  // grouped neighbor attention
  attn_kernel<<<8192, 256, 0, stream>>>(Qb, Kb, Vb, Ab);
  // out = attn @ Wo^T, f32 out
  gemm256_kernel<false><<<256, 512, 0, stream>>>(Ab, Wob, out, 4096, 4096, 4096);
}

// Round 13
// 803.737 us; speedup vs baseline: 1.0218x; 1.0218x over previous
//
#include <hip/hip_runtime.h>
#include <hip/hip_bf16.h>
#include <stdint.h>

#define DEV_INLINE __device__ __forceinline__

typedef __attribute__((ext_vector_type(4))) float f32x4;
typedef __attribute__((ext_vector_type(8))) __bf16 bf16x8;
typedef __attribute__((ext_vector_type(8))) unsigned short u16x8;

// problem dims
constexpr int Hh = 32, KVc = 8, Dd = 128, Gg = 4, Nn = 16;

DEV_INLINE unsigned short f32_to_bf16(float f) {
  unsigned u = __float_as_uint(f);
  u += 0x7fffu + ((u >> 16) & 1u);   // round-to-nearest-even
  return (unsigned short)(u >> 16);
}
DEV_INLINE float bf16_lo(unsigned u) { return __uint_as_float(u << 16); }
DEV_INLINE float bf16_hi(unsigned u) { return __uint_as_float(u & 0xffff0000u); }

// ---------------- merged cast f32 -> bf16 (6 segments, 1 launch) ----------
// r11 best-measured version. Per iteration each thread reads 32 B (2x f32x4)
// and writes 16 B (u16x8). Cast is memory-system-limited at ~3.9 TB/s
// logical for this 2:1 r:w mix (width and MLP unrolls both measured null).
__global__ __launch_bounds__(256) void cast_all_kernel(
    const float* __restrict__ s0, unsigned short* __restrict__ d0,   // hs
    const float* __restrict__ s1, unsigned short* __restrict__ d1,   // Wq
    const float* __restrict__ s2, unsigned short* __restrict__ d2,   // rhs
    const float* __restrict__ s3, unsigned short* __restrict__ d3,   // Wk
    const float* __restrict__ s4, unsigned short* __restrict__ d4,   // Wv
    const float* __restrict__ s5, unsigned short* __restrict__ d5,   // Wo
    float qscale) {
  const int b = blockIdx.x;
  const float* src; unsigned short* dst; int n8, b0, nb; float sc = 1.f;
  if (b < 512)       { src = s0; dst = d0; n8 = 2097152; b0 = 0;    nb = 512; }
  else if (b < 1024) { src = s1; dst = d1; n8 = 2097152; b0 = 512;  nb = 512; sc = qscale; }
  else if (b < 3072) { src = s2; dst = d2; n8 = 8388608; b0 = 1024; nb = 2048; }
  else if (b < 3104) { src = s3; dst = d3; n8 = 131072;  b0 = 3072; nb = 32; }
  else if (b < 3136) { src = s4; dst = d4; n8 = 131072;  b0 = 3104; nb = 32; }
  else               { src = s5; dst = d5; n8 = 2097152; b0 = 3136; nb = 512; }
  const f32x4* sp = reinterpret_cast<const f32x4*>(src);
  u16x8* dp = reinterpret_cast<u16x8*>(dst);
  const int stride = nb * 256;
  for (int i = (b - b0) * 256 + threadIdx.x; i < n8; i += stride) {
    f32x4 v0 = sp[2 * i];
    f32x4 v1 = sp[2 * i + 1];
    u16x8 o;
    o[0] = f32_to_bf16(v0.x * sc); o[1] = f32_to_bf16(v0.y * sc);
    o[2] = f32_to_bf16(v0.z * sc); o[3] = f32_to_bf16(v0.w * sc);
    o[4] = f32_to_bf16(v1.x * sc); o[5] = f32_to_bf16(v1.y * sc);
    o[6] = f32_to_bf16(v1.z * sc); o[7] = f32_to_bf16(v1.w * sc);
    dp[i] = o;
  }
}

// ---------------- GEMM body: C[M][N] = A[M][K] * B[N][K]^T ----------------
// r3 best-measured structure: 256x256 tile, BK=32, 512 threads (8 waves
// 2m x 4n), ring-4 LDS, 2-tile unrolled K-loop with register fragment
// double-buffering, counted lgkm/vm waits, setprio, XOR bank swizzle
// (0 conflicts measured), XCD-aware block swizzle. LDS passed in by the
// kernel so multiple call-sites share one allocation.
template <bool OUT_BF16>
DEV_INLINE void gemm256_body(const unsigned short* __restrict__ A,
                             const unsigned short* __restrict__ Bw,
                             void* __restrict__ Cout, int M, int N, int K,
                             int bid, int nwg,
                             unsigned short* AlsB, unsigned short* BlsB) {
  const int tid = threadIdx.x;
  const int wave = tid >> 6, lane = tid & 63;
  const int wm = wave >> 2, wn = wave & 3;       // 2 x 4 wave grid
  const int lrow = lane & 15, lhi = lane >> 4;
  const int swslot = (lhi ^ ((lrow >> 1) & 3)) << 4;

  // XCD-aware block swizzle (T1); nwg % 8 == 0 for all our grids
  const int ntn = N >> 8;
  const int swz = ((nwg & 7) == 0) ? ((bid & 7) * (nwg >> 3) + (bid >> 3)) : bid;
  const int tm = swz / ntn, tn = swz - tm * ntn;

  const unsigned short* Abase = A + (long)tm * 256 * K;
  const unsigned short* Bbase = Bw + (long)tn * 256 * K;
  const int ktiles = K >> 5;   // always even here (128 or 32)

  auto slotA = [&](int s) { return AlsB + s * 8192; };
  auto slotB = [&](int s) { return BlsB + s * 8192; };

  // stage one 256x32 bf16 tile; linear LDS dest, inverse-swizzled global src
  auto stage = [&](const unsigned short* gbase, unsigned short* lslot, int k0) {
#pragma unroll
    for (int j = 0; j < 2; ++j) {
      int c = (j << 9) + tid;              // chunk 0..1023 (16B each)
      int row = c >> 2;
      int gslot = (c & 3) ^ ((row >> 1) & 3);
      const unsigned short* g = gbase + (long)row * K + k0 + (gslot << 3);
      int ldsoff = (((j << 9) + (wave << 6)) << 4);  // wave-uniform base
      __builtin_amdgcn_global_load_lds(
          (const __attribute__((address_space(1))) unsigned int*)g,
          (__attribute__((address_space(3))) unsigned int*)((char*)lslot + ldsoff),
          16, 0, 0);
    }
  };

#define RD_B(dst, Bc)                                                      \
  _Pragma("unroll") for (int n = 0; n < 4; ++n) dst[n] =                   \
      *reinterpret_cast<const bf16x8*>(                                    \
          (Bc) + (((wn << 6) + (n << 4) + lrow) << 6) + swslot);
#define RD_A(dst, Ac, mh)                                                  \
  _Pragma("unroll") for (int m = 0; m < 4; ++m) dst[m] =                   \
      *reinterpret_cast<const bf16x8*>(                                    \
          (Ac) + (((wm << 7) + ((mh) << 6) + (m << 4) + lrow) << 6) + swslot);
#define MFMA16(accrow, af, bf)                                             \
  _Pragma("unroll") for (int m = 0; m < 4; ++m)                            \
  _Pragma("unroll") for (int n = 0; n < 4; ++n)                            \
      acc[(accrow) + m][n] = __builtin_amdgcn_mfma_f32_16x16x32_bf16(      \
          af[m], bf[n], acc[(accrow) + m][n], 0, 0, 0);

  f32x4 acc[8][4];
#pragma unroll
  for (int m = 0; m < 8; ++m)
#pragma unroll
    for (int n = 0; n < 4; ++n) acc[m][n] = {0.f, 0.f, 0.f, 0.f};

  // prologue: stage tiles 0..2, wait tile 0 landed, prefetch slot-0 frags
#pragma unroll
  for (int p = 0; p < 3; ++p) {
    if (p < ktiles) {
      stage(Abase, slotA(p), p << 5);
      stage(Bbase, slotB(p), p << 5);
    }
  }
  if (ktiles > 2) asm volatile("s_waitcnt vmcnt(8)" ::: "memory");
  else            asm volatile("s_waitcnt vmcnt(0)" ::: "memory");
  __builtin_amdgcn_s_barrier();

  bf16x8 bfrE[4], afrE[4], bfrO[4], afrO[4], afrH[4];
  RD_B(bfrE, (const char*)slotB(0));
  RD_A(afrE, (const char*)slotA(0), 0);

  for (int t0 = 0; t0 < ktiles; t0 += 2) {
    const int t1 = t0 + 1;
    const char* Ac1 = (const char*)slotA(t1 & 3);
    const char* Bc1 = (const char*)slotB(t1 & 3);
    const char* Ac0 = (const char*)slotA(t0 & 3);
    const int sp = (t0 + 3) & 3;   // ring slot for tiles t0+3 / t1+3

    // ---- P0: MFMA tile t0 m0-3; prefetch A m4-7(t0); stage A(t0+3) ----
    RD_A(afrH, Ac0, 1);
    if (t0 + 3 < ktiles) stage(Abase, slotA(sp), (t0 + 3) << 5);
    asm volatile("s_waitcnt lgkmcnt(4)" ::: "memory");  // bfrE/afrE ready
    __builtin_amdgcn_s_setprio(1);
    MFMA16(0, afrE, bfrE);
    __builtin_amdgcn_s_setprio(0);
    if (t0 + 3 < ktiles)      asm volatile("s_waitcnt vmcnt(6)" ::: "memory");
    else if (t0 + 2 < ktiles) asm volatile("s_waitcnt vmcnt(4)" ::: "memory");
    else                      asm volatile("s_waitcnt vmcnt(0)" ::: "memory");
    __builtin_amdgcn_s_barrier();   // tile t1 landed for everyone

    // ---- P1: MFMA tile t0 m4-7; prefetch frags(t1); stage B(t0+3) ----
    RD_B(bfrO, Bc1);
    RD_A(afrO, Ac1, 0);
    if (t0 + 3 < ktiles) stage(Bbase, slotB(sp), (t0 + 3) << 5);
    asm volatile("s_waitcnt lgkmcnt(8)" ::: "memory");  // afrH ready
    __builtin_amdgcn_s_setprio(1);
    MFMA16(4, afrH, bfrE);
    __builtin_amdgcn_s_setprio(0);
    __builtin_amdgcn_s_barrier();   // slot (t0-1) reads done -> P2 stage safe

    // ---- P2: MFMA tile t1 m0-3; prefetch A m4-7(t1); stage A(t1+3) ----
    RD_A(afrH, Ac1, 1);
    if (t1 + 3 < ktiles) stage(Abase, slotA(t0 & 3), (t1 + 3) << 5);
    asm volatile("s_waitcnt lgkmcnt(4)" ::: "memory");  // bfrO/afrO ready
    __builtin_amdgcn_s_setprio(1);
    MFMA16(0, afrO, bfrO);
    __builtin_amdgcn_s_setprio(0);
    if (t1 + 3 < ktiles)      asm volatile("s_waitcnt vmcnt(6)" ::: "memory");
    else if (t1 + 2 < ktiles) asm volatile("s_waitcnt vmcnt(4)" ::: "memory");
    else                      asm volatile("s_waitcnt vmcnt(0)" ::: "memory");
    __builtin_amdgcn_s_barrier();   // tile t0+2 landed for everyone

    // ---- P3: MFMA tile t1 m4-7; prefetch frags(t0+2); stage B(t1+3) ----
    if (t0 + 2 < ktiles) {
      const char* Bc2 = (const char*)slotB((t0 + 2) & 3);
      const char* Ac2 = (const char*)slotA((t0 + 2) & 3);
      RD_B(bfrE, Bc2);
      RD_A(afrE, Ac2, 0);
    }
    if (t1 + 3 < ktiles) stage(Bbase, slotB(t0 & 3), (t1 + 3) << 5);
    if (t0 + 2 < ktiles) asm volatile("s_waitcnt lgkmcnt(8)" ::: "memory");
    else                 asm volatile("s_waitcnt lgkmcnt(0)" ::: "memory");
    __builtin_amdgcn_s_setprio(1);
    MFMA16(4, afrH, bfrO);
    __builtin_amdgcn_s_setprio(0);
    __builtin_amdgcn_s_barrier();   // slot t0 reads done -> next P0 stage safe
  }

  // epilogue: C/D layout col = lane&15, row = (lane>>4)*4 + r
#pragma unroll
  for (int m = 0; m < 8; ++m) {
#pragma unroll
    for (int n = 0; n < 4; ++n) {
      long r0 = (long)tm * 256 + (wm << 7) + (m << 4) + (lhi << 2);
      long c0 = (long)tn * 256 + (wn << 6) + (n << 4) + lrow;
#pragma unroll
      for (int r = 0; r < 4; ++r) {
        float v = acc[m][n][r];
        if constexpr (OUT_BF16)
          ((unsigned short*)Cout)[(r0 + r) * N + c0] = f32_to_bf16(v);
        else
          ((float*)Cout)[(r0 + r) * N + c0] = v;
      }
    }
  }
#undef RD_A
#undef RD_B
#undef MFMA16
}

// merged Q/K/V GEMM: blocks [0,256) = Q (long blocks first for LPT packing),
// [256,1280) = K, [1280,2304) = V. One shared LDS allocation.
__global__ __launch_bounds__(512, 2) void gemm_qkv_kernel(
    const unsigned short* __restrict__ hsb, const unsigned short* __restrict__ Wqb,
    unsigned short* __restrict__ Qb,
    const unsigned short* __restrict__ rhsb,
    const unsigned short* __restrict__ Wkb, unsigned short* __restrict__ Kb,
    const unsigned short* __restrict__ Wvb, unsigned short* __restrict__ Vb) {
  __shared__ alignas(16) unsigned short Als[4][8192];
  __shared__ alignas(16) unsigned short Bls[4][8192];
  const int b = blockIdx.x;
  const unsigned short *Ap, *Bp; unsigned short* Cp; int M, N, K, bid, nwg;
  if (b < 256)       { Ap = hsb;  Bp = Wqb; Cp = Qb; M = 4096;  N = 4096; K = 4096; bid = b;        nwg = 256; }
  else if (b < 1280) { Ap = rhsb; Bp = Wkb; Cp = Kb; M = 65536; N = 1024; K = 1024; bid = b - 256;  nwg = 1024; }
  else               { Ap = rhsb; Bp = Wvb; Cp = Vb; M = 65536; N = 1024; K = 1024; bid = b - 1280; nwg = 1024; }
  gemm256_body<true>(Ap, Bp, Cp, M, N, K, bid, nwg, &Als[0][0], &Bls[0][0]);
}

// standalone GEMM (used for the f32-output out-projection)
template <bool OUT_BF16>
__global__ __launch_bounds__(512, 2) void gemm256_kernel(
    const unsigned short* __restrict__ A, const unsigned short* __restrict__ Bw,
    void* __restrict__ Cout, int M, int N, int K) {
  __shared__ alignas(16) unsigned short Als[4][8192];
  __shared__ alignas(16) unsigned short Bls[4][8192];
  gemm256_body<OUT_BF16>(A, Bw, Cout, M, N, K, blockIdx.x, gridDim.x,
                         &Als[0][0], &Bls[0][0]);
}

// ---------------- grouped neighbor attention ----------------
// one wave per (b*s, kv); lane = g*16 + i
__global__ __launch_bounds__(256) void attn_kernel(
    const unsigned short* __restrict__ Q,   // [B*S][H*D] bf16 (pre-scaled)
    const unsigned short* __restrict__ Kf,  // [B*S*N][KV*D] bf16
    const unsigned short* __restrict__ Vf,  // [B*S*N][KV*D] bf16
    unsigned short* __restrict__ O) {       // [B*S][H*D] bf16
  const int tid = threadIdx.x;
  const int wave = tid >> 6;
  const int lane = tid & 63;
  const int sl = blockIdx.x * 4 + wave;  // [0, B*S*KV)
  const int bs = sl >> 3;
  const int kv = sl & 7;
  const int g = lane >> 4;
  const int i = lane & 15;

  const unsigned short* qrow = Q + (long)bs * (Hh * Dd) + (kv * Gg + g) * Dd;
  const int ni = 2 * kv + (i >> 3);
  const unsigned short* krow =
      Kf + ((long)bs * Nn + ni) * (KVc * Dd) + (i & 7) * Dd;

  float s = 0.f;
#pragma unroll
  for (int c = 0; c < 16; ++c) {
    uint4 qu = *reinterpret_cast<const uint4*>(qrow + c * 8);
    uint4 ku = *reinterpret_cast<const uint4*>(krow + c * 8);
    s += bf16_lo(qu.x) * bf16_lo(ku.x) + bf16_hi(qu.x) * bf16_hi(ku.x);
    s += bf16_lo(qu.y) * bf16_lo(ku.y) + bf16_hi(qu.y) * bf16_hi(ku.y);
    s += bf16_lo(qu.z) * bf16_lo(ku.z) + bf16_hi(qu.z) * bf16_hi(ku.z);
    s += bf16_lo(qu.w) * bf16_lo(ku.w) + bf16_hi(qu.w) * bf16_hi(ku.w);
  }

  float mx = s;
#pragma unroll
  for (int off = 8; off >= 1; off >>= 1) mx = fmaxf(mx, __shfl_xor(mx, off));
  float p = __expf(s - mx);
  float sum = p;
#pragma unroll
  for (int off = 8; off >= 1; off >>= 1) sum += __shfl_xor(sum, off);
  p = p / sum;

  float o[8] = {0.f, 0.f, 0.f, 0.f, 0.f, 0.f, 0.f, 0.f};
  const long vbase = (long)bs * Nn * (KVc * Dd);
#pragma unroll
  for (int ii = 0; ii < 16; ++ii) {
    float pi = __shfl(p, (lane & 48) | ii);
    const unsigned short* vrow = Vf + vbase +
        (long)(2 * kv + (ii >> 3)) * (KVc * Dd) + (ii & 7) * Dd + i * 8;
    uint4 vu = *reinterpret_cast<const uint4*>(vrow);
    o[0] += pi * bf16_lo(vu.x); o[1] += pi * bf16_hi(vu.x);
    o[2] += pi * bf16_lo(vu.y); o[3] += pi * bf16_hi(vu.y);
    o[4] += pi * bf16_lo(vu.z); o[5] += pi * bf16_hi(vu.z);
    o[6] += pi * bf16_lo(vu.w); o[7] += pi * bf16_hi(vu.w);
  }
  u16x8 ov;
#pragma unroll
  for (int d = 0; d < 8; ++d) ov[d] = f32_to_bf16(o[d]);
  *reinterpret_cast<u16x8*>(O + (long)bs * (Hh * Dd) + (kv * Gg + g) * Dd +
                            i * 8) = ov;
}

// ---------------- launch ----------------
extern "C" void kernel_launch(void* const* d_in, const int* in_sizes, int n_in,
                              void* d_out, int out_size, void* d_ws,
                              size_t ws_size, hipStream_t stream) {
  (void)in_sizes; (void)n_in; (void)out_size; (void)ws_size;
  const float* hs = (const float*)d_in[0];   // [2,2048,4096]
  const float* rhs = (const float*)d_in[1];  // [2,2048,16,1024]
  const float* Wq = (const float*)d_in[2];   // [4096,4096]
  const float* Wk = (const float*)d_in[3];   // [1024,1024]
  const float* Wv = (const float*)d_in[4];   // [1024,1024]
  const float* Wo = (const float*)d_in[5];   // [4096,4096]
  float* out = (float*)d_out;                // [2,2048,4096] f32

  char* ws = (char*)d_ws;
  size_t off = 0;
  auto alloc = [&](size_t bytes) { char* p = ws + off; off += bytes; return p; };
  unsigned short* hsb  = (unsigned short*)alloc(16777216ull * 2);
  unsigned short* Wqb  = (unsigned short*)alloc(16777216ull * 2);
  unsigned short* rhsb = (unsigned short*)alloc(67108864ull * 2);
  unsigned short* Wkb  = (unsigned short*)alloc(1048576ull * 2);
  unsigned short* Wvb  = (unsigned short*)alloc(1048576ull * 2);
  unsigned short* Wob  = (unsigned short*)alloc(16777216ull * 2);
  unsigned short* Qb   = (unsigned short*)alloc(16777216ull * 2);
  unsigned short* Kb   = (unsigned short*)alloc(67108864ull * 2);
  unsigned short* Vb   = (unsigned short*)alloc(67108864ull * 2);
  unsigned short* Ab   = (unsigned short*)alloc(16777216ull * 2);

  const float scaler = 0.08838834764831845f;  // D^-0.5, folded into Wq

  // all six f32->bf16 casts in one launch (3648 blocks, block-partitioned)
  cast_all_kernel<<<3648, 256, 0, stream>>>(hs, hsb, Wq, Wqb, rhs, rhsb,
                                            Wk, Wkb, Wv, Wvb, Wo, Wob, scaler);

  // Q,K,V gemms merged into one dispatch (LPT packing: 256 long Q-blocks
  // first, then 2x1024 short K/V blocks backfill)
  gemm_qkv_kernel<<<2304, 512, 0, stream>>>(hsb, Wqb, Qb, rhsb, Wkb, Kb,
                                            Wvb, Vb);
  // grouped neighbor attention
  attn_kernel<<<8192, 256, 0, stream>>>(Qb, Kb, Vb, Ab);
  // out = attn @ Wo^T, f32 out
  gemm256_kernel<false><<<256, 512, 0, stream>>>(Ab, Wob, out, 4096, 4096, 4096);
}